// Round 6
// baseline (624.171 us; speedup 1.0000x reference)
//
#include <hip/hip_runtime.h>
#include <hip/hip_cooperative_groups.h>

namespace cg = cooperative_groups;

#define BS 2
#define NM 10
#define NA 8400
#define NC 80
#define NBIN 36
#define KTOP 13

// ------------------------------------------------------------------
// Single cooperative mega-kernel. Phases separated by grid.sync():
//  P0: zero d_out + ws arrays, AND build pair list (disjoint memory;
//      counter pre-zeroed by a hipMemsetAsync node before this kernel)
//  P1: per-pair dist_max(36) + IoU + align  (4 waves/pair, uniform scan)
//  P2: top-13 per (b,m)
//  P3: per-anchor finalize + fused pos_align/pos_ov atomics
//  P4: gt_dist masking + centerness + scores
// ------------------------------------------------------------------
__global__ __launch_bounds__(256, 4)
void k_mega(const float* __restrict__ pds, const float* __restrict__ pdb,
            const float* __restrict__ anc, const int* __restrict__ gl,
            const float* __restrict__ gtb, const float* __restrict__ mgt,
            const float* __restrict__ coor,
            float* __restrict__ out, float* __restrict__ wf){
  cg::grid_group grid = cg::this_grid();

  // ---- layout ----
  float* o_labels  = out;                    // 16800
  float* o_bboxes  = out + 16800;            // 67200
  float* o_scores  = out + 84000;            // 1344000
  float* o_maskpos = out + 1428000;          // 168000
  float* o_gtidx   = out + 1596000;          // 16800
  float* o_gtdist  = out + 1612800;          // 6048000
  float* o_cent    = out + 7660800;          // 168000
  float* o_fg      = out + 7828800;          // 16800

  int*   counter = (int*)wf;                 // wf[0] (memset to 0 pre-launch)
  float* w_align = wf + 16;                  // 168000
  float* w_ovl   = w_align + BS*NM*NA;       // 168000
  float* w_mask  = w_ovl + BS*NM*NA;         // 168000
  float* w_pa    = w_mask + BS*NM*NA;        // 20
  float* w_po    = w_pa + BS*NM;             // 20
  int*   w_pairs = (int*)(w_po + BS*NM);     // up to 168000

  __shared__ __align__(16) float spool[6672];   // 26.7 KB, aliased per phase

  int tid  = threadIdx.x;
  int lane = tid & 63, wave = tid >> 6;
  int gsz  = gridDim.x * 256;
  int gtid = blockIdx.x * 256 + tid;

  // ================= P0: zero + masklist =================
  {
    float4* out4 = (float4*)out;
    const int n4 = (16800+67200+1344000+168000+16800+6048000+168000+16800)/4;
    for (int i = gtid; i < n4; i += gsz) out4[i] = make_float4(0.f,0.f,0.f,0.f);
    float4* w4 = (float4*)(wf + 16);
    const int nw4 = (3*BS*NM*NA + 2*BS*NM)/4;
    for (int i = gtid; i < nw4; i += gsz) w4[i] = make_float4(0.f,0.f,0.f,0.f);
    for (int t = gtid; t < BS*NM*NA; t += gsz){
      int a = t % NA; int bm = t / NA;
      if (mgt[bm] <= 0.f) continue;
      float ax = anc[2*a], ay = anc[2*a+1];
      float lx = gtb[bm*4+0], ly = gtb[bm*4+1];
      float rx = gtb[bm*4+2], ry = gtb[bm*4+3];
      float mind = fminf(fminf(ax-lx, ay-ly), fminf(rx-ax, ry-ay));
      if (mind > 1e-9f){
        int i = atomicAdd(counter, 1);
        w_pairs[i] = t;
      }
    }
  }
  grid.sync();

  // ================= P1: dist =================
  {
    float2* s_da = (float2*)spool;        // 360 float2
    float*  s_m  = spool + 720;           // 36*33 floats
    int cnt = counter[0];
    for (int p = blockIdx.x; p < cnt; p += gridDim.x){
      int t = w_pairs[p];
      int a = t % NA; int bm = t / NA; int b = bm / NM;
      float ax = anc[2*a], ay = anc[2*a+1];
      const float* cc = coor + bm*720;
      for (int i = tid; i < 360; i += 256){
        float dx = cc[2*i]   - ax;
        float dy = cc[2*i+1] - ay;
        float dist = sqrtf(dx*dx + dy*dy);
        float an = atan2f(dy, dx) * 57.29577951308232f;
        if (an < 0.f) an += 360.f;
        s_da[i] = make_float2(dist, an);
      }
      __syncthreads();
      if (lane < NBIN){
        float th = (float)(lane*10);
        float v0=1e30f, v1=1e30f, v2=1e30f, v3=1e30f;
        float d0=0.f, d1=0.f, d2=0.f, d3=0.f;
        int base = wave*90;
        for (int k = 0; k < 90; k++){
          float2 da = s_da[base + k];
          float diff = fabsf(da.y - th);
          diff = fminf(diff, 360.f - diff);
          if (diff < v3){
            v3 = diff; d3 = da.x;
            if (v3 < v2){ float tv=v2; v2=v3; v3=tv; float td=d2; d2=d3; d3=td; }
            if (v2 < v1){ float tv=v1; v1=v2; v2=tv; float td=d1; d1=d2; d2=td; }
            if (v1 < v0){ float tv=v0; v0=v1; v1=tv; float td=d0; d0=d1; d1=td; }
          }
        }
        int mb = lane*33 + wave*8;
        s_m[mb+0]=v0; s_m[mb+1]=v1; s_m[mb+2]=v2; s_m[mb+3]=v3;
        s_m[mb+4]=d0; s_m[mb+5]=d1; s_m[mb+6]=d2; s_m[mb+7]=d3;
      }
      __syncthreads();
      if (wave == 0){
        float sum_min = 0.f, sum_max = 0.f;
        if (lane < NBIN){
          int mb = lane*33;
          float h0=s_m[mb+0], h1=s_m[mb+8], h2=s_m[mb+16], h3=s_m[mb+24];
          int p0=0, p1=0, p2=0, p3=0;
          float v0m = 0.f, dmax = 0.f;
#pragma unroll
          for (int step = 0; step < 4; step++){
            float bv = h0; int bw = 0;
            if (h1 < bv){ bv = h1; bw = 1; }
            if (h2 < bv){ bv = h2; bw = 2; }
            if (h3 < bv){ bv = h3; bw = 3; }
            float dd;
            if (bw == 0){ dd = s_m[mb+4+p0]; p0++; h0 = (p0<4)? s_m[mb+p0]    : 1e30f; }
            else if (bw == 1){ dd = s_m[mb+12+p1]; p1++; h1 = (p1<4)? s_m[mb+8+p1]  : 1e30f; }
            else if (bw == 2){ dd = s_m[mb+20+p2]; p2++; h2 = (p2<4)? s_m[mb+16+p2] : 1e30f; }
            else             { dd = s_m[mb+28+p3]; p3++; h3 = (p3<4)? s_m[mb+24+p3] : 1e30f; }
            if (step == 0) v0m = bv;
            dmax = fmaxf(dmax, dd);
          }
          float dm = (v0m > 3.0f) ? 1e-6f : dmax;
          float dfin = fmaxf(dm, 1e-6f);
          o_gtdist[(size_t)t*NBIN + lane] = dfin;
          float pr = pdb[((size_t)b*NA + a)*NBIN + lane];
          sum_max = fmaxf(dfin, pr);
          sum_min = fmaxf(fminf(dfin, pr), 1e-6f);
        }
        for (int off = 32; off > 0; off >>= 1){
          sum_min += __shfl_down(sum_min, off);
          sum_max += __shfl_down(sum_max, off);
        }
        if (lane == 0){
          float ov = sum_min / sum_max;
          int cls = gl[bm];
          float sc = pds[((size_t)b*NA + a)*NC + cls];
          w_align[t] = sc * ov * ov * ov;
          w_ovl[t]   = ov;
        }
      }
      __syncthreads();
    }
  }
  grid.sync();

  // ================= P2: topk (blocks 0..19) =================
  if (blockIdx.x < BS*NM){
    int bm = blockIdx.x;
    const float* al = w_align + (size_t)bm*NA;
    float* sv = spool;                       // 256*13
    int*   si = (int*)(spool + 3328);        // 256*13
    float* wv4 = spool + 6656;               // 4
    int*   wi4 = (int*)(spool + 6660);       // 4

    float v[KTOP]; int ix[KTOP];
#pragma unroll
    for (int j = 0; j < KTOP; j++){ v[j] = -1.f; ix[j] = 0x7fffffff; }
    for (int a = tid; a < NA; a += 256){
      float x = al[a];
      if (x > v[KTOP-1]){
        v[KTOP-1] = x; ix[KTOP-1] = a;
#pragma unroll
        for (int j = KTOP-1; j > 0; j--){
          if (v[j] > v[j-1]){
            float tv = v[j-1]; v[j-1] = v[j]; v[j] = tv;
            int   ti = ix[j-1]; ix[j-1] = ix[j]; ix[j] = ti;
          }
        }
      }
    }
#pragma unroll
    for (int j = 0; j < KTOP; j++){ sv[tid*KTOP+j] = v[j]; si[tid*KTOP+j] = ix[j]; }

    int head = 0;
    for (int r = 0; r < KTOP; r++){
      float cv = sv[tid*KTOP + head];
      int   ci = si[tid*KTOP + head];
      float rv = cv; int ri = ci;
      for (int off = 32; off > 0; off >>= 1){
        float ov = __shfl_down(rv, off);
        int   oi = __shfl_down(ri, off);
        if (ov > rv || (ov == rv && oi < ri)){ rv = ov; ri = oi; }
      }
      if (lane == 0){ wv4[wave] = rv; wi4[wave] = ri; }
      __syncthreads();
      float Wv = wv4[0]; int Wi = wi4[0];
#pragma unroll
      for (int w = 1; w < 4; w++){
        float ov = wv4[w]; int oi = wi4[w];
        if (ov > Wv || (ov == Wv && oi < Wi)){ Wv = ov; Wi = oi; }
      }
      if (ci == Wi && head < KTOP-1) head++;
      if (tid == 0 && Wv > 0.f) w_mask[(size_t)bm*NA + Wi] = 1.f;
      __syncthreads();
    }
  }
  grid.sync();

  // ================= P3: finalize =================
  for (int t = gtid; t < BS*NA; t += gsz){
    int a = t % NA, b = t / NA;
    float mp[NM];
    int fg = 0;
#pragma unroll
    for (int m = 0; m < NM; m++){
      mp[m] = w_mask[((size_t)(b*NM+m))*NA + a];
      fg += (mp[m] > 0.f) ? 1 : 0;
    }
    if (fg > 1){
      float bv = -1.f; int bi = 0;
#pragma unroll
      for (int m = 0; m < NM; m++){
        float v = w_ovl[((size_t)(b*NM+m))*NA + a];
        if (v > bv){ bv = v; bi = m; }
      }
#pragma unroll
      for (int m = 0; m < NM; m++){
        mp[m] = (m == bi) ? 1.f : 0.f;
        w_mask[((size_t)(b*NM+m))*NA + a] = mp[m];
      }
      fg = 1;
    }
    int tgt = 0;
#pragma unroll
    for (int m = NM-1; m >= 0; m--) if (mp[m] > 0.f) tgt = m;
#pragma unroll
    for (int m = 0; m < NM; m++) o_maskpos[((size_t)(b*NM+m))*NA + a] = mp[m];
    o_gtidx[t] = (float)tgt;
    o_fg[t] = (fg > 0) ? 1.f : 0.f;
    int lbl = gl[b*NM + tgt]; if (lbl < 0) lbl = 0;
    o_labels[t] = (float)lbl;
    const float* bx = gtb + (b*NM + tgt)*4;
    ((float4*)o_bboxes)[t] = make_float4(bx[0], bx[1], bx[2], bx[3]);
    if (fg > 0){
      int bmx = b*NM + tgt;
      float av  = w_align[(size_t)bmx*NA + a];
      float ovv = w_ovl[(size_t)bmx*NA + a];
      atomicMax((unsigned int*)&w_pa[bmx], __float_as_uint(av));
      atomicMax((unsigned int*)&w_po[bmx], __float_as_uint(ovv));
    }
  }
  grid.sync();

  // ================= P4: fix (gt_dist mask + centerness) + scores =================
  {
    int cnt = counter[0];
    int wid = blockIdx.x*4 + wave;
    int nw  = gridDim.x*4;
    for (int p = wid; p < cnt; p += nw){
      int t = w_pairs[p];
      float m = w_mask[t];
      float* row = o_gtdist + (size_t)t*NBIN;
      if (m > 0.f){
        float vmin = 1e30f, vmax = 0.f;
        if (lane < NBIN){
          float v = row[lane];
          vmin = v; vmax = v;
        }
        for (int off = 32; off > 0; off >>= 1){
          vmin = fminf(vmin, __shfl_down(vmin, off));
          vmax = fmaxf(vmax, __shfl_down(vmax, off));
        }
        if (lane == 0) o_cent[t] = sqrtf(vmin / vmax);
      } else {
        if (lane < NBIN) row[lane] = 0.f;
      }
    }
    for (int t = gtid; t < BS*NA; t += gsz){
      if (o_fg[t] > 0.f){
        int a = t % NA, b = t / NA;
        int m = (int)o_gtidx[t];
        int bm = b*NM + m;
        float av = w_align[(size_t)bm*NA + a];
        float norm = av * w_po[bm] / (w_pa[bm] + 1e-9f);
        int lbl = (int)o_labels[t];
        o_scores[(size_t)t*NC + lbl] = norm;
      }
    }
  }
}

extern "C" void kernel_launch(void* const* d_in, const int* in_sizes, int n_in,
                              void* d_out, int out_size, void* d_ws, size_t ws_size,
                              hipStream_t stream){
  const float* pds  = (const float*)d_in[0]; // (2,8400,80)
  const float* pdb  = (const float*)d_in[1]; // (2,8400,36)
  const float* anc  = (const float*)d_in[2]; // (8400,2)
  const int*   gl   = (const int*)  d_in[3]; // (2,10,1)
  const float* gtb  = (const float*)d_in[4]; // (2,10,4)
  const float* mgt  = (const float*)d_in[5]; // (2,10,1)
  const float* coor = (const float*)d_in[6]; // (2,10,720)

  float* out = (float*)d_out;
  float* wf  = (float*)d_ws;

  // counter must be 0 before the mega-kernel's P0 atomics
  hipMemsetAsync(wf, 0, 4, stream);

  // co-residency-safe grid for cooperative launch
  int nb = 0;
  hipOccupancyMaxActiveBlocksPerMultiprocessor(&nb, (const void*)k_mega, 256, 0);
  if (nb < 1) nb = 1;
  int grid = nb * 256;             // 256 CUs on MI355X
  if (grid > 1024) grid = 1024;
  if (grid < 256)  grid = 256;

  void* args[] = { (void*)&pds, (void*)&pdb, (void*)&anc, (void*)&gl,
                   (void*)&gtb, (void*)&mgt, (void*)&coor,
                   (void*)&out, (void*)&wf };
  hipLaunchCooperativeKernel((const void*)k_mega, dim3(grid), dim3(256),
                             args, 0, stream);
}

// Round 7
// 191.002 us; speedup vs baseline: 3.2679x; 3.2679x over previous
//
#include <hip/hip_runtime.h>

#define BS 2
#define NM 10
#define NA 8400
#define NC 80
#define NBIN 36
#define KTOP 13
#define NRECT (BS*NM*3)   // 60 rects: (bm, level)

// ---------------------------------------------------------------
// Closed-form pair enumeration: anchors inside box (bm) at level lv
// form an integer rectangle. Endpoints are corrected with the exact
// float test the reference uses ((xi+0.5f)*s - lx > 1e-9f etc.), and
// anchor coords (xi+0.5)*s are bit-exact equal to anc[] (pow2 scale),
// so membership == per-anchor test membership exactly.
// ---------------------------------------------------------------
__device__ __forceinline__ void rect_setup(int tid,
    const float* __restrict__ gtb, const float* __restrict__ mgt,
    int* sx0, int* sy0, int* scx, int* scum, int* sn, int* sbase){
  if (tid < NRECT){
    int bm = tid/3, lv = tid - bm*3;
    int cnt = 0, x0 = 0, y0 = 0, cx = 0, n = 0, base = 0;
    if (mgt[bm] > 0.f){
      float s = (float)(8 << lv);
      n = 640 >> (3 + lv);                     // 80, 40, 20
      base = (lv == 0) ? 0 : ((lv == 1) ? 6400 : 8000);
      float lx = gtb[bm*4+0], ly = gtb[bm*4+1];
      float rx = gtb[bm*4+2], ry = gtb[bm*4+3];
      int a0 = (int)ceilf(lx/s - 0.5f); a0 = min(max(a0, 0), n);
      while (a0 > 0   &&  (((a0-1)+0.5f)*s - lx > 1e-9f)) a0--;
      while (a0 < n   && !(((a0  )+0.5f)*s - lx > 1e-9f)) a0++;
      int a1 = (int)floorf(rx/s - 0.5f); a1 = min(max(a1, -1), n-1);
      while (a1 < n-1 &&  (rx - ((a1+1)+0.5f)*s > 1e-9f)) a1++;
      while (a1 >= 0  && !(rx - ((a1  )+0.5f)*s > 1e-9f)) a1--;
      int b0 = (int)ceilf(ly/s - 0.5f); b0 = min(max(b0, 0), n);
      while (b0 > 0   &&  (((b0-1)+0.5f)*s - ly > 1e-9f)) b0--;
      while (b0 < n   && !(((b0  )+0.5f)*s - ly > 1e-9f)) b0++;
      int b1 = (int)floorf(ry/s - 0.5f); b1 = min(max(b1, -1), n-1);
      while (b1 < n-1 &&  (ry - ((b1+1)+0.5f)*s > 1e-9f)) b1++;
      while (b1 >= 0  && !(ry - ((b1  )+0.5f)*s > 1e-9f)) b1--;
      cx = max(0, a1 - a0 + 1);
      int cy = max(0, b1 - b0 + 1);
      cnt = cx * cy;
      x0 = a0; y0 = b0;
    }
    sx0[tid] = x0; sy0[tid] = y0; scx[tid] = cx;
    scum[tid] = cnt; sn[tid] = n; sbase[tid] = base;
  }
  __syncthreads();
  if (tid == 0){
    int acc = 0;
    for (int r = 0; r < NRECT; r++){ int c = scum[r]; scum[r] = acc; acc += c; }
    scum[NRECT] = acc;
  }
  __syncthreads();
}

__device__ __forceinline__ int pair_from_p(int p,
    const int* sx0, const int* sy0, const int* scx,
    const int* scum, const int* sn, const int* sbase){
  int r = 0;
  while (r < NRECT-1 && scum[r+1] <= p) r++;
  int idx = p - scum[r];
  int cx = scx[r];
  int yi = idx / cx;
  int xi = idx - yi*cx;
  int a = sbase[r] + (sy0[r] + yi)*sn[r] + (sx0[r] + xi);
  int bm = r/3;
  return bm*NA + a;
}

// ---------------------------------------------------------------
// k_dist: fused zeroing + per-pair dist_max(36) + IoU + align.
// Loop 1 (thread-per-element): zero o_scores, o_cent, w_pa/w_po,
//   w_mask (all t), and for NON-pair t: w_align, w_ovl, gt_dist row.
// Loop 2 (block-per-pair, 4 waves/pair uniform scan): computed values.
// Disjoint address sets -> no intra-kernel race.
// ---------------------------------------------------------------
__global__ __launch_bounds__(256)
void k_dist(const float* __restrict__ pds, const float* __restrict__ pdb,
            const float* __restrict__ anc, const int* __restrict__ gl,
            const float* __restrict__ gtb, const float* __restrict__ mgt,
            const float* __restrict__ coor,
            float* __restrict__ out, float* __restrict__ wf){
  float* o_scores  = out + 84000;
  float* o_gtdist  = out + 1612800;
  float* o_cent    = out + 7660800;
  float* w_align = wf + 16;
  float* w_ovl   = w_align + BS*NM*NA;
  float* w_mask  = w_ovl + BS*NM*NA;
  float* w_pa    = w_mask + BS*NM*NA;   // + w_po contiguous (40 floats)

  __shared__ int sx0[NRECT], sy0[NRECT], scx[NRECT], scum[NRECT+1], sn[NRECT], sbase[NRECT];
  __shared__ float2 s_da[360];
  __shared__ float  s_m[NBIN*33];

  int tid = threadIdx.x;
  int lane = tid & 63, wave = tid >> 6;
  int gsz  = gridDim.x * 256;
  int gtid = blockIdx.x * 256 + tid;

  rect_setup(tid, gtb, mgt, sx0, sy0, scx, scum, sn, sbase);
  int total = scum[NRECT];

  // ---- loop 1: zeroing ----
  {
    float4 z = make_float4(0.f, 0.f, 0.f, 0.f);
    float4* sc4 = (float4*)o_scores;
    for (int i = gtid; i < (BS*NA*NC)/4; i += gsz) sc4[i] = z;
    float4* ce4 = (float4*)o_cent;
    for (int i = gtid; i < (BS*NM*NA)/4; i += gsz) ce4[i] = z;
    if (gtid < 2*BS*NM) w_pa[gtid] = 0.f;
    for (int t = gtid; t < BS*NM*NA; t += gsz){
      int a = t % NA; int bm = t / NA;
      w_mask[t] = 0.f;
      bool inpair = false;
      if (mgt[bm] > 0.f){
        float ax = anc[2*a], ay = anc[2*a+1];
        float lx = gtb[bm*4+0], ly = gtb[bm*4+1];
        float rx = gtb[bm*4+2], ry = gtb[bm*4+3];
        float mind = fminf(fminf(ax-lx, ay-ly), fminf(rx-ax, ry-ay));
        inpair = (mind > 1e-9f);
      }
      if (!inpair){
        w_align[t] = 0.f;
        w_ovl[t]   = 0.f;
        float4* row = (float4*)(o_gtdist + (size_t)t*NBIN);
#pragma unroll
        for (int j = 0; j < 9; j++) row[j] = z;
      }
    }
  }

  // ---- loop 2: per-pair compute ----
  for (int p = blockIdx.x; p < total; p += gridDim.x){
    int t = pair_from_p(p, sx0, sy0, scx, scum, sn, sbase);
    int a = t % NA; int bm = t / NA; int b = bm / NM;
    float ax = anc[2*a], ay = anc[2*a+1];
    const float* cc = coor + bm*720;
    for (int i = tid; i < 360; i += 256){
      float dx = cc[2*i]   - ax;
      float dy = cc[2*i+1] - ay;
      float dist = sqrtf(dx*dx + dy*dy);
      float an = atan2f(dy, dx) * 57.29577951308232f;
      if (an < 0.f) an += 360.f;
      s_da[i] = make_float2(dist, an);
    }
    __syncthreads();
    if (lane < NBIN){
      float th = (float)(lane*10);
      float v0=1e30f, v1=1e30f, v2=1e30f, v3=1e30f;
      float d0=0.f, d1=0.f, d2=0.f, d3=0.f;
      int base = wave*90;
      for (int k = 0; k < 90; k++){
        float2 da = s_da[base + k];
        float diff = fabsf(da.y - th);
        diff = fminf(diff, 360.f - diff);
        if (diff < v3){
          v3 = diff; d3 = da.x;
          if (v3 < v2){ float tv=v2; v2=v3; v3=tv; float td=d2; d2=d3; d3=td; }
          if (v2 < v1){ float tv=v1; v1=v2; v2=tv; float td=d1; d1=d2; d2=td; }
          if (v1 < v0){ float tv=v0; v0=v1; v1=tv; float td=d0; d0=d1; d1=td; }
        }
      }
      int mb = lane*33 + wave*8;
      s_m[mb+0]=v0; s_m[mb+1]=v1; s_m[mb+2]=v2; s_m[mb+3]=v3;
      s_m[mb+4]=d0; s_m[mb+5]=d1; s_m[mb+6]=d2; s_m[mb+7]=d3;
    }
    __syncthreads();
    if (wave == 0){
      float sum_min = 0.f, sum_max = 0.f;
      if (lane < NBIN){
        int mb = lane*33;
        float h0=s_m[mb+0], h1=s_m[mb+8], h2=s_m[mb+16], h3=s_m[mb+24];
        int p0=0, p1=0, p2=0, p3=0;
        float v0m = 0.f, dmax = 0.f;
#pragma unroll
        for (int step = 0; step < 4; step++){
          float bv = h0; int bw = 0;
          if (h1 < bv){ bv = h1; bw = 1; }
          if (h2 < bv){ bv = h2; bw = 2; }
          if (h3 < bv){ bv = h3; bw = 3; }
          float dd;
          if (bw == 0){ dd = s_m[mb+4+p0]; p0++; h0 = (p0<4)? s_m[mb+p0]    : 1e30f; }
          else if (bw == 1){ dd = s_m[mb+12+p1]; p1++; h1 = (p1<4)? s_m[mb+8+p1]  : 1e30f; }
          else if (bw == 2){ dd = s_m[mb+20+p2]; p2++; h2 = (p2<4)? s_m[mb+16+p2] : 1e30f; }
          else             { dd = s_m[mb+28+p3]; p3++; h3 = (p3<4)? s_m[mb+24+p3] : 1e30f; }
          if (step == 0) v0m = bv;
          dmax = fmaxf(dmax, dd);
        }
        float dm = (v0m > 3.0f) ? 1e-6f : dmax;
        float dfin = fmaxf(dm, 1e-6f);
        o_gtdist[(size_t)t*NBIN + lane] = dfin;
        float pr = pdb[((size_t)b*NA + a)*NBIN + lane];
        sum_max = fmaxf(dfin, pr);
        sum_min = fmaxf(fminf(dfin, pr), 1e-6f);
      }
      for (int off = 32; off > 0; off >>= 1){
        sum_min += __shfl_down(sum_min, off);
        sum_max += __shfl_down(sum_max, off);
      }
      if (lane == 0){
        float ov = sum_min / sum_max;
        int cls = gl[bm];
        float sc = pds[((size_t)b*NA + a)*NC + cls];
        w_align[t] = sc * ov * ov * ov;
        w_ovl[t]   = ov;
      }
    }
    __syncthreads();
  }
}

// ---------------- top-13 per (b,m): single pass + 512-wide k-way merge --------
__global__ __launch_bounds__(512)
void k_topk(const float* __restrict__ w_align, float* __restrict__ w_mask){
  int bm = blockIdx.x;
  const float* al = w_align + (size_t)bm*NA;
  int tid = threadIdx.x;
  __shared__ float sv[512*KTOP];
  __shared__ int   si[512*KTOP];
  __shared__ float wv8[8];
  __shared__ int   wi8[8];

  float v[KTOP]; int ix[KTOP];
#pragma unroll
  for (int j = 0; j < KTOP; j++){ v[j] = -1.f; ix[j] = 0x7fffffff; }
  for (int a = tid; a < NA; a += 512){
    float x = al[a];
    if (x > v[KTOP-1]){
      v[KTOP-1] = x; ix[KTOP-1] = a;
#pragma unroll
      for (int j = KTOP-1; j > 0; j--){
        if (v[j] > v[j-1]){
          float tv = v[j-1]; v[j-1] = v[j]; v[j] = tv;
          int   ti = ix[j-1]; ix[j-1] = ix[j]; ix[j] = ti;
        }
      }
    }
  }
#pragma unroll
  for (int j = 0; j < KTOP; j++){ sv[tid*KTOP+j] = v[j]; si[tid*KTOP+j] = ix[j]; }

  int head = 0;
  int lane = tid & 63, wave = tid >> 6;
  for (int r = 0; r < KTOP; r++){
    float cv = sv[tid*KTOP + head];
    int   ci = si[tid*KTOP + head];
    float rv = cv; int ri = ci;
    for (int off = 32; off > 0; off >>= 1){
      float ov = __shfl_down(rv, off);
      int   oi = __shfl_down(ri, off);
      if (ov > rv || (ov == rv && oi < ri)){ rv = ov; ri = oi; }
    }
    if (lane == 0){ wv8[wave] = rv; wi8[wave] = ri; }
    __syncthreads();
    float Wv = wv8[0]; int Wi = wi8[0];
#pragma unroll
    for (int w = 1; w < 8; w++){
      float ov = wv8[w]; int oi = wi8[w];
      if (ov > Wv || (ov == Wv && oi < Wi)){ Wv = ov; Wi = oi; }
    }
    if (ci == Wi && head < KTOP-1) head++;
    if (tid == 0 && Wv > 0.f) w_mask[(size_t)bm*NA + Wi] = 1.f;
    __syncthreads();
  }
}

// ---------------- per-anchor finalize (+ fused pos_align/pos_ov atomics) ------
__global__ void k_final(const float* __restrict__ w_align, const float* __restrict__ w_ovl,
                        float* __restrict__ w_mask,
                        const int* __restrict__ gl, const float* __restrict__ gtb,
                        float* __restrict__ o_labels, float* __restrict__ o_bboxes,
                        float* __restrict__ o_maskpos, float* __restrict__ o_gtidx,
                        float* __restrict__ o_fg,
                        float* __restrict__ w_pa, float* __restrict__ w_po){
  int t = blockIdx.x*256 + threadIdx.x;
  if (t >= BS*NA) return;
  int a = t % NA, b = t / NA;
  float mp[NM];
  int fg = 0;
#pragma unroll
  for (int m = 0; m < NM; m++){
    mp[m] = w_mask[((size_t)(b*NM+m))*NA + a];
    fg += (mp[m] > 0.f) ? 1 : 0;
  }
  if (fg > 1){
    float bv = -1.f; int bi = 0;
#pragma unroll
    for (int m = 0; m < NM; m++){
      float v = w_ovl[((size_t)(b*NM+m))*NA + a];
      if (v > bv){ bv = v; bi = m; }
    }
#pragma unroll
    for (int m = 0; m < NM; m++){
      mp[m] = (m == bi) ? 1.f : 0.f;
      w_mask[((size_t)(b*NM+m))*NA + a] = mp[m];
    }
    fg = 1;
  }
  int tgt = 0;
#pragma unroll
  for (int m = NM-1; m >= 0; m--) if (mp[m] > 0.f) tgt = m;
#pragma unroll
  for (int m = 0; m < NM; m++) o_maskpos[((size_t)(b*NM+m))*NA + a] = mp[m];
  o_gtidx[t] = (float)tgt;
  o_fg[t] = (fg > 0) ? 1.f : 0.f;
  int lbl = gl[b*NM + tgt]; if (lbl < 0) lbl = 0;
  o_labels[t] = (float)lbl;
  const float* bx = gtb + (b*NM + tgt)*4;
  ((float4*)o_bboxes)[t] = make_float4(bx[0], bx[1], bx[2], bx[3]);
  if (fg > 0){
    int bmx = b*NM + tgt;
    float av  = w_align[(size_t)bmx*NA + a];
    float ovv = w_ovl[(size_t)bmx*NA + a];
    atomicMax((unsigned int*)&w_pa[bmx], __float_as_uint(av));
    atomicMax((unsigned int*)&w_po[bmx], __float_as_uint(ovv));
  }
}

// ---------------- fused tail: (A) gt_dist mask + centerness, (B) scores ------
#define NB_FIX 512
__global__ void k_fuse(const float* __restrict__ gtb, const float* __restrict__ mgt,
                       const float* __restrict__ w_mask, float* __restrict__ o_gtdist,
                       float* __restrict__ o_cent,
                       const float* __restrict__ w_align,
                       const float* __restrict__ w_pa, const float* __restrict__ w_po,
                       const float* __restrict__ o_labels, const float* __restrict__ o_fg,
                       const float* __restrict__ o_gtidx, float* __restrict__ o_scores){
  if (blockIdx.x < NB_FIX){
    __shared__ int sx0[NRECT], sy0[NRECT], scx[NRECT], scum[NRECT+1], sn[NRECT], sbase[NRECT];
    int tid = threadIdx.x;
    rect_setup(tid, gtb, mgt, sx0, sy0, scx, scum, sn, sbase);
    int total = scum[NRECT];
    int lane = tid & 63, wave = tid >> 6;
    for (int p = blockIdx.x*4 + wave; p < total; p += NB_FIX*4){
      int t = pair_from_p(p, sx0, sy0, scx, scum, sn, sbase);
      float m = w_mask[t];
      float* row = o_gtdist + (size_t)t*NBIN;
      if (m > 0.f){
        float vmin = 1e30f, vmax = 0.f;
        if (lane < NBIN){
          float v = row[lane];
          vmin = v; vmax = v;
        }
        for (int off = 32; off > 0; off >>= 1){
          vmin = fminf(vmin, __shfl_down(vmin, off));
          vmax = fmaxf(vmax, __shfl_down(vmax, off));
        }
        if (lane == 0) o_cent[t] = sqrtf(vmin / vmax);
      } else {
        if (lane < NBIN) row[lane] = 0.f;
      }
    }
  } else {
    int t = (blockIdx.x - NB_FIX)*256 + threadIdx.x;
    if (t < BS*NA && o_fg[t] > 0.f){
      int a = t % NA, b = t / NA;
      int m = (int)o_gtidx[t];
      int bm = b*NM + m;
      float av = w_align[(size_t)bm*NA + a];
      float norm = av * w_po[bm] / (w_pa[bm] + 1e-9f);
      int lbl = (int)o_labels[t];
      o_scores[(size_t)t*NC + lbl] = norm;
    }
  }
}

extern "C" void kernel_launch(void* const* d_in, const int* in_sizes, int n_in,
                              void* d_out, int out_size, void* d_ws, size_t ws_size,
                              hipStream_t stream){
  const float* pds  = (const float*)d_in[0]; // (2,8400,80)
  const float* pdb  = (const float*)d_in[1]; // (2,8400,36)
  const float* anc  = (const float*)d_in[2]; // (8400,2)
  const int*   gl   = (const int*)  d_in[3]; // (2,10,1)
  const float* gtb  = (const float*)d_in[4]; // (2,10,4)
  const float* mgt  = (const float*)d_in[5]; // (2,10,1)
  const float* coor = (const float*)d_in[6]; // (2,10,720)

  float* out = (float*)d_out;
  float* o_labels  = out;                                 // 16800
  float* o_bboxes  = o_labels + BS*NA;                    // 67200
  float* o_scores  = o_bboxes + BS*NA*4;                  // 1344000
  float* o_maskpos = o_scores + (size_t)BS*NA*NC;         // 168000
  float* o_gtidx   = o_maskpos + BS*NM*NA;                // 16800
  float* o_gtdist  = o_gtidx + BS*NA;                     // 6048000
  float* o_cent    = o_gtdist + (size_t)BS*NM*NA*NBIN;    // 168000
  float* o_fg      = o_cent + BS*NM*NA;                   // 16800

  float* wf      = (float*)d_ws;
  float* w_align = wf + 16;
  float* w_ovl   = w_align + BS*NM*NA;
  float* w_mask  = w_ovl + BS*NM*NA;
  float* w_pa    = w_mask + BS*NM*NA;
  float* w_po    = w_pa + BS*NM;

  k_dist<<<4096, 256, 0, stream>>>(pds, pdb, anc, gl, gtb, mgt, coor, out, wf);
  k_topk<<<BS*NM, 512, 0, stream>>>(w_align, w_mask);
  k_final<<<(BS*NA+255)/256, 256, 0, stream>>>(w_align, w_ovl, w_mask, gl, gtb,
                                               o_labels, o_bboxes, o_maskpos, o_gtidx, o_fg,
                                               w_pa, w_po);
  k_fuse<<<NB_FIX + (BS*NA+255)/256, 256, 0, stream>>>(gtb, mgt, w_mask,
                                                       o_gtdist, o_cent,
                                                       w_align, w_pa, w_po,
                                                       o_labels, o_fg, o_gtidx, o_scores);
}

// Round 8
// 181.826 us; speedup vs baseline: 3.4328x; 1.0505x over previous
//
#include <hip/hip_runtime.h>

#define BS 2
#define NM 10
#define NA 8400
#define NC 80
#define NBIN 36
#define KTOP 13
#define NRECT (BS*NM*3)   // 60 rects: (bm, level)

// ---------------------------------------------------------------
// Closed-form in-box anchor rectangle for (bm, lv), endpoint-corrected
// with the exact float test the reference uses; membership is exact.
// ---------------------------------------------------------------
__device__ __forceinline__ void rect_one(int bm, int lv,
    const float* __restrict__ gtb, const float* __restrict__ mgt,
    int& x0, int& y0, int& cx, int& cnt, int& n, int& base){
  cnt = 0; x0 = 0; y0 = 0; cx = 0; n = 0; base = 0;
  if (mgt[bm] > 0.f){
    float s = (float)(8 << lv);
    n = 640 >> (3 + lv);                     // 80, 40, 20
    base = (lv == 0) ? 0 : ((lv == 1) ? 6400 : 8000);
    float lx = gtb[bm*4+0], ly = gtb[bm*4+1];
    float rx = gtb[bm*4+2], ry = gtb[bm*4+3];
    int a0 = (int)ceilf(lx/s - 0.5f); a0 = min(max(a0, 0), n);
    while (a0 > 0   &&  (((a0-1)+0.5f)*s - lx > 1e-9f)) a0--;
    while (a0 < n   && !(((a0  )+0.5f)*s - lx > 1e-9f)) a0++;
    int a1 = (int)floorf(rx/s - 0.5f); a1 = min(max(a1, -1), n-1);
    while (a1 < n-1 &&  (rx - ((a1+1)+0.5f)*s > 1e-9f)) a1++;
    while (a1 >= 0  && !(rx - ((a1  )+0.5f)*s > 1e-9f)) a1--;
    int b0 = (int)ceilf(ly/s - 0.5f); b0 = min(max(b0, 0), n);
    while (b0 > 0   &&  (((b0-1)+0.5f)*s - ly > 1e-9f)) b0--;
    while (b0 < n   && !(((b0  )+0.5f)*s - ly > 1e-9f)) b0++;
    int b1 = (int)floorf(ry/s - 0.5f); b1 = min(max(b1, -1), n-1);
    while (b1 < n-1 &&  (ry - ((b1+1)+0.5f)*s > 1e-9f)) b1++;
    while (b1 >= 0  && !(ry - ((b1  )+0.5f)*s > 1e-9f)) b1--;
    cx = max(0, a1 - a0 + 1);
    int cy = max(0, b1 - b0 + 1);
    cnt = cx * cy;
    x0 = a0; y0 = b0;
  }
}

__device__ __forceinline__ void rect_setup(int tid,
    const float* __restrict__ gtb, const float* __restrict__ mgt,
    int* sx0, int* sy0, int* scx, int* scum, int* sn, int* sbase){
  if (tid < NRECT){
    int bm = tid/3, lv = tid - bm*3;
    int x0, y0, cx, cnt, n, base;
    rect_one(bm, lv, gtb, mgt, x0, y0, cx, cnt, n, base);
    sx0[tid] = x0; sy0[tid] = y0; scx[tid] = cx;
    scum[tid] = cnt; sn[tid] = n; sbase[tid] = base;
  }
  __syncthreads();
  if (tid == 0){
    int acc = 0;
    for (int r = 0; r < NRECT; r++){ int c = scum[r]; scum[r] = acc; acc += c; }
    scum[NRECT] = acc;
  }
  __syncthreads();
}

__device__ __forceinline__ int pair_from_p(int p,
    const int* sx0, const int* sy0, const int* scx,
    const int* scum, const int* sn, const int* sbase){
  int r = 0;
  while (r < NRECT-1 && scum[r+1] <= p) r++;
  int idx = p - scum[r];
  int cx = scx[r];
  int yi = idx / cx;
  int xi = idx - yi*cx;
  int a = sbase[r] + (sy0[r] + yi)*sn[r] + (sx0[r] + xi);
  int bm = r/3;
  return bm*NA + a;
}

__device__ __forceinline__ bool in_pair(int t,
    const float* __restrict__ anc, const float* __restrict__ gtb,
    const float* __restrict__ mgt){
  int a = t % NA; int bm = t / NA;
  if (mgt[bm] <= 0.f) return false;
  float ax = anc[2*a], ay = anc[2*a+1];
  float lx = gtb[bm*4+0], ly = gtb[bm*4+1];
  float rx = gtb[bm*4+2], ry = gtb[bm*4+3];
  float mind = fminf(fminf(ax-lx, ay-ly), fminf(rx-ax, ry-ay));
  return (mind > 1e-9f);
}

// ---------------------------------------------------------------
// k_dist: fused zeroing (coalesced) + per-pair dist_max(36) + IoU + align.
// ---------------------------------------------------------------
__global__ __launch_bounds__(256)
void k_dist(const float* __restrict__ pds, const float* __restrict__ pdb,
            const float* __restrict__ anc, const int* __restrict__ gl,
            const float* __restrict__ gtb, const float* __restrict__ mgt,
            const float* __restrict__ coor,
            float* __restrict__ out, float* __restrict__ wf){
  float* o_scores  = out + 84000;
  float* o_gtdist  = out + 1612800;
  float* o_cent    = out + 7660800;
  float* w_align = wf + 16;
  float* w_ovl   = w_align + BS*NM*NA;
  float* w_mask  = w_ovl + BS*NM*NA;
  float* w_pa    = w_mask + BS*NM*NA;   // + w_po contiguous (40 floats)

  __shared__ int sx0[NRECT], sy0[NRECT], scx[NRECT], scum[NRECT+1], sn[NRECT], sbase[NRECT];
  __shared__ float2 s_da[360];
  __shared__ float  s_m[NBIN*33];

  int tid = threadIdx.x;
  int lane = tid & 63, wave = tid >> 6;
  int gsz  = gridDim.x * 256;
  int gtid = blockIdx.x * 256 + tid;

  rect_setup(tid, gtb, mgt, sx0, sy0, scx, scum, sn, sbase);
  int total = scum[NRECT];

  // ---- loop 1: zeroing (all coalesced / exec-masked coalesced) ----
  {
    float4 z = make_float4(0.f, 0.f, 0.f, 0.f);
    float4* sc4 = (float4*)o_scores;
    for (int i = gtid; i < (BS*NA*NC)/4; i += gsz) sc4[i] = z;
    float4* ce4 = (float4*)o_cent;
    for (int i = gtid; i < (BS*NM*NA)/4; i += gsz) ce4[i] = z;
    if (gtid < 2*BS*NM) w_pa[gtid] = 0.f;
    for (int t = gtid; t < BS*NM*NA; t += gsz){
      w_mask[t] = 0.f;
      if (!in_pair(t, anc, gtb, mgt)){
        w_align[t] = 0.f;
        w_ovl[t]   = 0.f;
      }
    }
    // gt_dist: flat float4 index -> consecutive lanes hit consecutive lines
    float4* gd4 = (float4*)o_gtdist;
    for (int i = gtid; i < (BS*NM*NA*NBIN)/4; i += gsz){
      int t = i / 9;          // 9 float4 per 36-float row
      if (!in_pair(t, anc, gtb, mgt)) gd4[i] = z;
    }
  }

  // ---- loop 2: per-pair compute (4 waves/pair uniform scan) ----
  for (int p = blockIdx.x; p < total; p += gridDim.x){
    int t = pair_from_p(p, sx0, sy0, scx, scum, sn, sbase);
    int a = t % NA; int bm = t / NA; int b = bm / NM;
    float ax = anc[2*a], ay = anc[2*a+1];
    const float* cc = coor + bm*720;
    for (int i = tid; i < 360; i += 256){
      float dx = cc[2*i]   - ax;
      float dy = cc[2*i+1] - ay;
      float dist = sqrtf(dx*dx + dy*dy);
      float an = atan2f(dy, dx) * 57.29577951308232f;
      if (an < 0.f) an += 360.f;
      s_da[i] = make_float2(dist, an);
    }
    __syncthreads();
    if (lane < NBIN){
      float th = (float)(lane*10);
      float v0=1e30f, v1=1e30f, v2=1e30f, v3=1e30f;
      float d0=0.f, d1=0.f, d2=0.f, d3=0.f;
      int base = wave*90;
      for (int k = 0; k < 90; k++){
        float2 da = s_da[base + k];
        float diff = fabsf(da.y - th);
        diff = fminf(diff, 360.f - diff);
        if (diff < v3){
          v3 = diff; d3 = da.x;
          if (v3 < v2){ float tv=v2; v2=v3; v3=tv; float td=d2; d2=d3; d3=td; }
          if (v2 < v1){ float tv=v1; v1=v2; v2=tv; float td=d1; d1=d2; d2=td; }
          if (v1 < v0){ float tv=v0; v0=v1; v1=tv; float td=d0; d0=d1; d1=td; }
        }
      }
      int mb = lane*33 + wave*8;
      s_m[mb+0]=v0; s_m[mb+1]=v1; s_m[mb+2]=v2; s_m[mb+3]=v3;
      s_m[mb+4]=d0; s_m[mb+5]=d1; s_m[mb+6]=d2; s_m[mb+7]=d3;
    }
    __syncthreads();
    if (wave == 0){
      float sum_min = 0.f, sum_max = 0.f;
      if (lane < NBIN){
        int mb = lane*33;
        float h0=s_m[mb+0], h1=s_m[mb+8], h2=s_m[mb+16], h3=s_m[mb+24];
        int p0=0, p1=0, p2=0, p3=0;
        float v0m = 0.f, dmax = 0.f;
#pragma unroll
        for (int step = 0; step < 4; step++){
          float bv = h0; int bw = 0;
          if (h1 < bv){ bv = h1; bw = 1; }
          if (h2 < bv){ bv = h2; bw = 2; }
          if (h3 < bv){ bv = h3; bw = 3; }
          float dd;
          if (bw == 0){ dd = s_m[mb+4+p0]; p0++; h0 = (p0<4)? s_m[mb+p0]    : 1e30f; }
          else if (bw == 1){ dd = s_m[mb+12+p1]; p1++; h1 = (p1<4)? s_m[mb+8+p1]  : 1e30f; }
          else if (bw == 2){ dd = s_m[mb+20+p2]; p2++; h2 = (p2<4)? s_m[mb+16+p2] : 1e30f; }
          else             { dd = s_m[mb+28+p3]; p3++; h3 = (p3<4)? s_m[mb+24+p3] : 1e30f; }
          if (step == 0) v0m = bv;
          dmax = fmaxf(dmax, dd);
        }
        float dm = (v0m > 3.0f) ? 1e-6f : dmax;
        float dfin = fmaxf(dm, 1e-6f);
        o_gtdist[(size_t)t*NBIN + lane] = dfin;
        float pr = pdb[((size_t)b*NA + a)*NBIN + lane];
        sum_max = fmaxf(dfin, pr);
        sum_min = fmaxf(fminf(dfin, pr), 1e-6f);
      }
      for (int off = 32; off > 0; off >>= 1){
        sum_min += __shfl_down(sum_min, off);
        sum_max += __shfl_down(sum_max, off);
      }
      if (lane == 0){
        float ov = sum_min / sum_max;
        int cls = gl[bm];
        float sc = pds[((size_t)b*NA + a)*NC + cls];
        w_align[t] = sc * ov * ov * ov;
        w_ovl[t]   = ov;
      }
    }
    __syncthreads();
  }
}

// ---------------- top-13 per (b,m): rect-local candidates only --------------
__global__ __launch_bounds__(256)
void k_topk(const float* __restrict__ gtb, const float* __restrict__ mgt,
            const float* __restrict__ w_align, float* __restrict__ w_mask){
  int bm = blockIdx.x;
  const float* al = w_align + (size_t)bm*NA;
  int tid = threadIdx.x;
  __shared__ int rx0[3], ry0[3], rcx[3], rcum[4], rn[3], rbase[3];
  __shared__ float sv[256*KTOP];
  __shared__ int   si[256*KTOP];
  __shared__ float wv4[4];
  __shared__ int   wi4[4];

  if (tid < 3){
    int x0, y0, cx, cnt, n, base;
    rect_one(bm, tid, gtb, mgt, x0, y0, cx, cnt, n, base);
    rx0[tid]=x0; ry0[tid]=y0; rcx[tid]=cx; rcum[tid]=cnt; rn[tid]=n; rbase[tid]=base;
  }
  __syncthreads();
  if (tid == 0){
    int acc = 0;
#pragma unroll
    for (int r = 0; r < 3; r++){ int c = rcum[r]; rcum[r] = acc; acc += c; }
    rcum[3] = acc;
  }
  __syncthreads();
  int total = rcum[3];

  // per-thread top-13 over rect-local candidates (a ascending per thread)
  float v[KTOP]; int ix[KTOP];
#pragma unroll
  for (int j = 0; j < KTOP; j++){ v[j] = -1.f; ix[j] = 0x7fffffff; }
  for (int p = tid; p < total; p += 256){
    int r = (p >= rcum[1]) + (p >= rcum[2]);
    int idx = p - rcum[r];
    int cx = rcx[r];
    int yi = idx / cx;
    int xi = idx - yi*cx;
    int a = rbase[r] + (ry0[r] + yi)*rn[r] + (rx0[r] + xi);
    float x = al[a];
    if (x > v[KTOP-1]){
      v[KTOP-1] = x; ix[KTOP-1] = a;
#pragma unroll
      for (int j = KTOP-1; j > 0; j--){
        if (v[j] > v[j-1]){
          float tv = v[j-1]; v[j-1] = v[j]; v[j] = tv;
          int   ti = ix[j-1]; ix[j-1] = ix[j]; ix[j] = ti;
        }
      }
    }
  }
#pragma unroll
  for (int j = 0; j < KTOP; j++){ sv[tid*KTOP+j] = v[j]; si[tid*KTOP+j] = ix[j]; }

  int head = 0;
  int lane = tid & 63, wave = tid >> 6;
  for (int r = 0; r < KTOP; r++){
    float cv = sv[tid*KTOP + head];
    int   ci = si[tid*KTOP + head];
    float rv = cv; int ri = ci;
    for (int off = 32; off > 0; off >>= 1){
      float ov = __shfl_down(rv, off);
      int   oi = __shfl_down(ri, off);
      if (ov > rv || (ov == rv && oi < ri)){ rv = ov; ri = oi; }
    }
    if (lane == 0){ wv4[wave] = rv; wi4[wave] = ri; }
    __syncthreads();
    float Wv = wv4[0]; int Wi = wi4[0];
#pragma unroll
    for (int w = 1; w < 4; w++){
      float ov = wv4[w]; int oi = wi4[w];
      if (ov > Wv || (ov == Wv && oi < Wi)){ Wv = ov; Wi = oi; }
    }
    if (ci == Wi && head < KTOP-1) head++;
    if (tid == 0 && Wv > 0.f) w_mask[(size_t)bm*NA + Wi] = 1.f;
    __syncthreads();
  }
}

// ---------------- per-anchor finalize (+ fused pos_align/pos_ov atomics) ------
__global__ void k_final(const float* __restrict__ w_align, const float* __restrict__ w_ovl,
                        float* __restrict__ w_mask,
                        const int* __restrict__ gl, const float* __restrict__ gtb,
                        float* __restrict__ o_labels, float* __restrict__ o_bboxes,
                        float* __restrict__ o_maskpos, float* __restrict__ o_gtidx,
                        float* __restrict__ o_fg,
                        float* __restrict__ w_pa, float* __restrict__ w_po){
  int t = blockIdx.x*256 + threadIdx.x;
  if (t >= BS*NA) return;
  int a = t % NA, b = t / NA;
  float mp[NM];
  int fg = 0;
#pragma unroll
  for (int m = 0; m < NM; m++){
    mp[m] = w_mask[((size_t)(b*NM+m))*NA + a];
    fg += (mp[m] > 0.f) ? 1 : 0;
  }
  if (fg > 1){
    float bv = -1.f; int bi = 0;
#pragma unroll
    for (int m = 0; m < NM; m++){
      float v = w_ovl[((size_t)(b*NM+m))*NA + a];
      if (v > bv){ bv = v; bi = m; }
    }
#pragma unroll
    for (int m = 0; m < NM; m++){
      mp[m] = (m == bi) ? 1.f : 0.f;
      w_mask[((size_t)(b*NM+m))*NA + a] = mp[m];
    }
    fg = 1;
  }
  int tgt = 0;
#pragma unroll
  for (int m = NM-1; m >= 0; m--) if (mp[m] > 0.f) tgt = m;
#pragma unroll
  for (int m = 0; m < NM; m++) o_maskpos[((size_t)(b*NM+m))*NA + a] = mp[m];
  o_gtidx[t] = (float)tgt;
  o_fg[t] = (fg > 0) ? 1.f : 0.f;
  int lbl = gl[b*NM + tgt]; if (lbl < 0) lbl = 0;
  o_labels[t] = (float)lbl;
  const float* bx = gtb + (b*NM + tgt)*4;
  ((float4*)o_bboxes)[t] = make_float4(bx[0], bx[1], bx[2], bx[3]);
  if (fg > 0){
    int bmx = b*NM + tgt;
    float av  = w_align[(size_t)bmx*NA + a];
    float ovv = w_ovl[(size_t)bmx*NA + a];
    atomicMax((unsigned int*)&w_pa[bmx], __float_as_uint(av));
    atomicMax((unsigned int*)&w_po[bmx], __float_as_uint(ovv));
  }
}

// ---------------- fused tail: (A) gt_dist mask + centerness, (B) scores ------
#define NB_FIX 512
__global__ void k_fuse(const float* __restrict__ gtb, const float* __restrict__ mgt,
                       const float* __restrict__ w_mask, float* __restrict__ o_gtdist,
                       float* __restrict__ o_cent,
                       const float* __restrict__ w_align,
                       const float* __restrict__ w_pa, const float* __restrict__ w_po,
                       const float* __restrict__ o_labels, const float* __restrict__ o_fg,
                       const float* __restrict__ o_gtidx, float* __restrict__ o_scores){
  if (blockIdx.x < NB_FIX){
    __shared__ int sx0[NRECT], sy0[NRECT], scx[NRECT], scum[NRECT+1], sn[NRECT], sbase[NRECT];
    int tid = threadIdx.x;
    rect_setup(tid, gtb, mgt, sx0, sy0, scx, scum, sn, sbase);
    int total = scum[NRECT];
    int lane = tid & 63, wave = tid >> 6;
    for (int p = blockIdx.x*4 + wave; p < total; p += NB_FIX*4){
      int t = pair_from_p(p, sx0, sy0, scx, scum, sn, sbase);
      float m = w_mask[t];
      float* row = o_gtdist + (size_t)t*NBIN;
      if (m > 0.f){
        float vmin = 1e30f, vmax = 0.f;
        if (lane < NBIN){
          float v = row[lane];
          vmin = v; vmax = v;
        }
        for (int off = 32; off > 0; off >>= 1){
          vmin = fminf(vmin, __shfl_down(vmin, off));
          vmax = fmaxf(vmax, __shfl_down(vmax, off));
        }
        if (lane == 0) o_cent[t] = sqrtf(vmin / vmax);
      } else {
        if (lane < NBIN) row[lane] = 0.f;
      }
    }
  } else {
    int t = (blockIdx.x - NB_FIX)*256 + threadIdx.x;
    if (t < BS*NA && o_fg[t] > 0.f){
      int a = t % NA, b = t / NA;
      int m = (int)o_gtidx[t];
      int bm = b*NM + m;
      float av = w_align[(size_t)bm*NA + a];
      float norm = av * w_po[bm] / (w_pa[bm] + 1e-9f);
      int lbl = (int)o_labels[t];
      o_scores[(size_t)t*NC + lbl] = norm;
    }
  }
}

extern "C" void kernel_launch(void* const* d_in, const int* in_sizes, int n_in,
                              void* d_out, int out_size, void* d_ws, size_t ws_size,
                              hipStream_t stream){
  const float* pds  = (const float*)d_in[0]; // (2,8400,80)
  const float* pdb  = (const float*)d_in[1]; // (2,8400,36)
  const float* anc  = (const float*)d_in[2]; // (8400,2)
  const int*   gl   = (const int*)  d_in[3]; // (2,10,1)
  const float* gtb  = (const float*)d_in[4]; // (2,10,4)
  const float* mgt  = (const float*)d_in[5]; // (2,10,1)
  const float* coor = (const float*)d_in[6]; // (2,10,720)

  float* out = (float*)d_out;
  float* o_labels  = out;                                 // 16800
  float* o_bboxes  = o_labels + BS*NA;                    // 67200
  float* o_scores  = o_bboxes + BS*NA*4;                  // 1344000
  float* o_maskpos = o_scores + (size_t)BS*NA*NC;         // 168000
  float* o_gtidx   = o_maskpos + BS*NM*NA;                // 16800
  float* o_gtdist  = o_gtidx + BS*NA;                     // 6048000
  float* o_cent    = o_gtdist + (size_t)BS*NM*NA*NBIN;    // 168000
  float* o_fg      = o_cent + BS*NM*NA;                   // 16800

  float* wf      = (float*)d_ws;
  float* w_align = wf + 16;
  float* w_ovl   = w_align + BS*NM*NA;
  float* w_mask  = w_ovl + BS*NM*NA;
  float* w_pa    = w_mask + BS*NM*NA;
  float* w_po    = w_pa + BS*NM;

  k_dist<<<4096, 256, 0, stream>>>(pds, pdb, anc, gl, gtb, mgt, coor, out, wf);
  k_topk<<<BS*NM, 256, 0, stream>>>(gtb, mgt, w_align, w_mask);
  k_final<<<(BS*NA+255)/256, 256, 0, stream>>>(w_align, w_ovl, w_mask, gl, gtb,
                                               o_labels, o_bboxes, o_maskpos, o_gtidx, o_fg,
                                               w_pa, w_po);
  k_fuse<<<NB_FIX + (BS*NA+255)/256, 256, 0, stream>>>(gtb, mgt, w_mask,
                                                       o_gtdist, o_cent,
                                                       w_align, w_pa, w_po,
                                                       o_labels, o_fg, o_gtidx, o_scores);
}